// Round 3
// baseline (2090.017 us; speedup 1.0000x reference)
//
#include <hip/hip_runtime.h>
#include <math.h>

// ---------------- scan / CSR build ----------------

__global__ void k_count(const int* __restrict__ dst, int* __restrict__ counts, int E){
  int e = blockIdx.x*256 + threadIdx.x;
  if (e < E) atomicAdd(&counts[dst[e]], 1);
}

__global__ void k_scan1(const int* __restrict__ cnt, int* __restrict__ excl,
                        int* __restrict__ bsum, int N){
  __shared__ int sm[1024];
  int tid = threadIdx.x, gid = blockIdx.x*1024 + tid;
  int v = (gid < N) ? cnt[gid] : 0;
  sm[tid] = v; __syncthreads();
  for (int off=1; off<1024; off<<=1){
    int t = (tid >= off) ? sm[tid-off] : 0;
    __syncthreads();
    sm[tid] += t;
    __syncthreads();
  }
  if (gid < N) excl[gid] = sm[tid] - v;
  if (tid == 1023) bsum[blockIdx.x] = sm[tid];
}

__global__ void k_scan2(int* __restrict__ bsum, int NB){
  __shared__ int sm[1024];
  int tid = threadIdx.x;
  int v = (tid < NB) ? bsum[tid] : 0;
  sm[tid] = v; __syncthreads();
  for (int off=1; off<1024; off<<=1){
    int t = (tid >= off) ? sm[tid-off] : 0;
    __syncthreads();
    sm[tid] += t;
    __syncthreads();
  }
  if (tid < NB) bsum[tid] = sm[tid] - v;
}

__global__ void k_scan3(const int* __restrict__ excl, const int* __restrict__ bsum,
                        int* __restrict__ offsets, int* __restrict__ cursor, int N, int E){
  int gid = blockIdx.x*1024 + threadIdx.x;
  if (gid < N){ int o = excl[gid] + bsum[gid>>10]; offsets[gid] = o; cursor[gid] = o; }
  if (gid == N) offsets[N] = E;
}

__global__ void k_geom(const int* __restrict__ esrc, const int* __restrict__ edst,
                       int* __restrict__ cursor, int* __restrict__ csr_src,
                       int* __restrict__ csr_dst, int E){
  int e = blockIdx.x*256 + threadIdx.x;
  if (e >= E) return;
  int d = edst[e];
  int p = atomicAdd(&cursor[d], 1);
  csr_src[p] = esrc[e];
  csr_dst[p] = d;
}

// ---------------- shared per-edge math ----------------

__device__ __forceinline__ void edge_shw(
    int s, int d, const float* __restrict__ pos,
    const int* __restrict__ types, const float* sEmb,
    const float* sW1, const float* sW2, float* shw_out /*9*/){
  float px = pos[3*d]-pos[3*s], py = pos[3*d+1]-pos[3*s+1], pz = pos[3*d+2]-pos[3*s+2];
  float r = sqrtf(px*px + py*py + pz*pz);
  float rm = fmaxf(r, 1e-9f);
  float inv = 1.f/rm;
  float ux = px*inv, uy = py*inv, uz = pz*inv;
  const float c1 = 1.7320508075688772f, c2 = 3.872983346207417f, c2b = 1.118033988749895f;
  float sh[9];
  sh[0]=1.f; sh[1]=c1*uy; sh[2]=c1*uz; sh[3]=c1*ux;
  sh[4]=c2*ux*uy; sh[5]=c2*uy*uz; sh[6]=c2b*(3.f*uz*uz-1.f); sh[7]=c2*ux*uz;
  sh[8]=0.5f*c2*(ux*ux-uy*uy);
  float ee[18];
  int ts_ = types[s], td_ = types[d];
  #pragma unroll
  for (int i=0;i<4;i++){ ee[i] = sEmb[td_*4+i]; ee[4+i] = sEmb[ts_*4+i]; }
  float xx = r * 0.2f;                    // r / CUTOFF
  float x2v = xx*xx, x3v = x2v*xx, x6 = x3v*x3v, x7 = x6*xx, x8 = x7*xx;
  float env = 1.f - 28.f*x6 + 48.f*x7 - 21.f*x8;
  const float bc = 0.6324555320336759f;   // sqrt(2/5)
  float pref = bc * env * inv;
  const float PI = 3.14159265358979323846f;
  float s1, cth;
  __sincosf(PI*xx, &s1, &cth);
  float two_c = 2.f*cth;
  float sp = 0.f, sc = s1;                // sin(0), sin(pi x)
  ee[8] = pref * sc;
  #pragma unroll
  for (int n=2;n<=10;n++){
    float sn = two_c*sc - sp;             // sin(n pi x) recurrence
    sp = sc; sc = sn;
    ee[7+n] = pref * sc;
  }
  float h[10];
  #pragma unroll
  for (int j=0;j<10;j++){
    float a = 0.f;
    #pragma unroll
    for (int k=0;k<18;k++) a = fmaf(ee[k], sW1[k*10+j], a);
    h[j] = fmaxf(a, 0.f);
  }
  #pragma unroll
  for (int sj=0;sj<9;sj++){
    float a = 0.f;
    #pragma unroll
    for (int j=0;j<10;j++) a = fmaf(h[j], sW2[j*9+sj], a);
    shw_out[sj] = sh[sj]*a;
  }
}

// ---------------- per-layer: shw in CSR order (layers 1 & 2) ----------------

__global__ __launch_bounds__(256) void k_shw(
    const int* __restrict__ csr_src, const int* __restrict__ csr_dst,
    const float* __restrict__ pos, const int* __restrict__ types,
    const float* __restrict__ embed,
    const float* __restrict__ w1, const float* __restrict__ w2,
    float* __restrict__ shw, int E){
  __shared__ float sEmb[16];
  __shared__ float sW1[180];
  __shared__ float sW2[90];
  int t = threadIdx.x;
  if (t < 16) sEmb[t] = embed[t];
  if (t < 180) sW1[t] = w1[t];
  if (t < 90)  sW2[t] = w2[t];
  __syncthreads();
  int p = blockIdx.x*256 + t;
  if (p >= E) return;
  float sw[9];
  edge_shw(csr_src[p], csr_dst[p], pos, types, sEmb, sW1, sW2, sw);
  #pragma unroll
  for (int sj=0;sj<9;sj++) shw[(size_t)p*9+sj] = sw[sj];
}

// ---------------- layer 3: scatter G[src,s] += shw3[e,s]  (natural edge order) ----------------

__global__ __launch_bounds__(256) void k_g3(
    const int* __restrict__ esrc, const int* __restrict__ edst,
    const float* __restrict__ pos, const int* __restrict__ types,
    const float* __restrict__ embed,
    const float* __restrict__ w1, const float* __restrict__ w2,
    float* __restrict__ G, int E){
  __shared__ float sEmb[16];
  __shared__ float sW1[180];
  __shared__ float sW2[90];
  int t = threadIdx.x;
  if (t < 16) sEmb[t] = embed[t];
  if (t < 180) sW1[t] = w1[t];
  if (t < 90)  sW2[t] = w2[t];
  __syncthreads();
  int e = blockIdx.x*256 + t;
  if (e >= E) return;
  int s = esrc[e];
  float sw[9];
  edge_shw(s, edst[e], pos, types, sEmb, sW1, sW2, sw);
  float* gr = G + (size_t)s*9;
  #pragma unroll
  for (int sj=0;sj<9;sj++) atomicAdd(&gr[sj], sw[sj]);
}

// ---------------- layer 3 finish: out = 0.25 * sum_n sum_s G[n,s]*(x2[n].tp3[s]) ----------------

__global__ __launch_bounds__(256) void k_final(
    const float* __restrict__ G, const float* __restrict__ x2,
    const float* __restrict__ tp3, float* __restrict__ out, int N){
  __shared__ float tl[684];
  int t = threadIdx.x;
  for (int i=t;i<684;i+=256) tl[i] = tp3[i]*0.25f;
  __syncthreads();
  int n = blockIdx.x*256 + t;
  float part = 0.f;
  if (n < N){
    const float* xr = x2 + (size_t)n*76;
    float accs[9];
    #pragma unroll
    for (int s=0;s<9;s++) accs[s]=0.f;
    #pragma unroll
    for (int i4=0;i4<19;i4++){
      float4 xv = *(const float4*)&xr[i4*4];
      #pragma unroll
      for (int s=0;s<9;s++){
        const float* tp = &tl[s*76 + i4*4];
        accs[s] = fmaf(xv.x, tp[0], accs[s]);
        accs[s] = fmaf(xv.y, tp[1], accs[s]);
        accs[s] = fmaf(xv.z, tp[2], accs[s]);
        accs[s] = fmaf(xv.w, tp[3], accs[s]);
      }
    }
    const float* gr = G + (size_t)n*9;
    #pragma unroll
    for (int s=0;s<9;s++) part = fmaf(accs[s], gr[s], part);
  }
  #pragma unroll
  for (int off=32; off>0; off>>=1) part += __shfl_down(part, off, 64);
  if ((t & 63) == 0) atomicAdd(out, part);
}

// ---------------- layer 1: thread-per-dest (Z is 36 regs) + gate + residual ----------------

__global__ __launch_bounds__(256) void k_layer1(
    const int* __restrict__ offsets, const int* __restrict__ csr_src,
    const float* __restrict__ shw1, const int* __restrict__ types,
    const float* __restrict__ embed, const float* __restrict__ tp1,
    float* __restrict__ x1, int N){
  __shared__ float sT[36*92];
  __shared__ float sEmb[16];
  int t = threadIdx.x;
  if (t < 16) sEmb[t] = embed[t];
  for (int i=t; i<36*92; i+=256) sT[i] = tp1[i]*0.25f;   // fold 1/sqrt(AVG_DEG)
  __syncthreads();
  int d = blockIdx.x*256 + t;
  if (d >= N) return;
  float Z[36];
  #pragma unroll
  for (int i=0;i<36;i++) Z[i]=0.f;
  int b0 = offsets[d], b1 = offsets[d+1];
  for (int j=b0;j<b1;j++){
    int sn = csr_src[j];
    int tt = types[sn];
    float x0[4];
    #pragma unroll
    for (int i=0;i<4;i++) x0[i] = sEmb[tt*4+i];
    #pragma unroll
    for (int si=0;si<9;si++){
      float sw = shw1[(size_t)j*9+si];
      #pragma unroll
      for (int i=0;i<4;i++) Z[si*4+i] = fmaf(sw, x0[i], Z[si*4+i]);
    }
  }
  float sact[12];
  #pragma unroll
  for (int c=0;c<12;c++){
    float y=0.f;
    #pragma unroll
    for (int p=0;p<36;p++) y = fmaf(Z[p], sT[p*92+c], y);
    sact[c] = (c<4) ? fmaxf(y,0.f) : fabsf(y);
  }
  float gact[16];
  #pragma unroll
  for (int c=0;c<16;c++){
    float y=0.f;
    #pragma unroll
    for (int p=0;p<36;p++) y = fmaf(Z[p], sT[p*92+12+c], y);
    gact[c] = (c<4 || (c>=8 && c<12)) ? fmaxf(y,0.f) : tanhf(y);
  }
  int td = types[d];
  float* xo = x1 + (size_t)d*76;
  #pragma unroll
  for (int c=0;c<12;c++) xo[c] = sact[c] + (c<4 ? sEmb[td*4+c] : 0.f);
  #pragma unroll
  for (int j=0;j<64;j++){
    float y=0.f;
    #pragma unroll
    for (int p=0;p<36;p++) y = fmaf(Z[p], sT[p*92+28+j], y);
    int gi = (j<24) ? (j/3) : (8 + (j-24)/5);
    xo[12+j] = y*gact[gi];
  }
}

// ---------------- layer 2 stage A: wave-per-dest Z accumulation (lane = feature) ----------------

__global__ __launch_bounds__(256) void k_conv2(
    const int* __restrict__ offsets, const int* __restrict__ csr_src,
    const float* __restrict__ shw2, const float* __restrict__ x1,
    float* __restrict__ Z2, int d0, int dend){
  int lane = threadIdx.x & 63;
  int d = d0 + blockIdx.x*4 + (threadIdx.x >> 6);
  if (d >= dend) return;
  float z[9], zb[9];
  #pragma unroll
  for (int s=0;s<9;s++){ z[s]=0.f; zb[s]=0.f; }
  bool hi = lane < 12;
  int b0 = offsets[d], b1 = offsets[d+1];
  for (int j=b0;j<b1;j++){
    int sn = csr_src[j];                       // wave-uniform
    const float* xr = x1 + (size_t)sn*76;
    float xa = xr[lane];
    float xb = hi ? xr[64+lane] : 0.f;
    #pragma unroll
    for (int s=0;s<9;s++){
      float sw = shw2[(size_t)j*9+s];          // wave-uniform broadcast
      z[s]  = fmaf(sw, xa, z[s]);
      zb[s] = fmaf(sw, xb, zb[s]);
    }
  }
  float* zr = Z2 + (size_t)(d - d0)*704;
  #pragma unroll
  for (int s=0;s<9;s++){
    zr[s*76+lane] = z[s];
    if (hi) zr[s*76+64+lane] = zb[s];
  }
  if (lane < 20) zr[684+lane] = 0.f;           // K padding 684->704
}

// ---------------- layer 2 stage B: (chunk x 704) @ (704 x 96) GEMM + gate + residual ----------------

__global__ void k_wprep(const float* __restrict__ tp2, float* __restrict__ W){
  int q = blockIdx.x*256 + threadIdx.x;
  if (q >= 704*96) return;
  int k = q/96, f = q - 96*k;
  W[q] = (k < 684 && f < 92) ? tp2[k*92+f]*0.25f : 0.f;
}

__global__ __launch_bounds__(256) void k_gemm2(
    const float* __restrict__ Z2, const float* __restrict__ W,
    const float* __restrict__ x1, float* __restrict__ x2, int d0, int dend){
  __shared__ float lz[64][68];
  __shared__ float lw[64][100];
  int t = threadIdx.x;
  int mb = blockIdx.x*64;          // row within chunk
  int m0 = d0 + mb;                // global node
  int tf = t & 31, tg = t >> 5;
  float acc[8][3];
  #pragma unroll
  for (int a=0;a<8;a++)
    #pragma unroll
    for (int b=0;b<3;b++) acc[a][b]=0.f;
  for (int c=0;c<11;c++){
    #pragma unroll
    for (int j=0;j<4;j++){
      int q = j*256+t; int m = q>>4, k4 = q&15;
      *(float4*)&lz[m][k4*4] = *(const float4*)&Z2[(size_t)(mb+m)*704 + c*64 + k4*4];
    }
    #pragma unroll
    for (int j=0;j<6;j++){
      int q = j*256+t; int k = q/24, f4 = q - k*24;
      *(float4*)&lw[k][f4*4] = *(const float4*)&W[(size_t)(c*64+k)*96 + f4*4];
    }
    __syncthreads();
    #pragma unroll 2
    for (int kk=0; kk<64; kk+=4){
      float av[8][4];
      #pragma unroll
      for (int mi=0;mi<8;mi++) *(float4*)av[mi] = *(const float4*)&lz[tg*8+mi][kk];
      #pragma unroll
      for (int u=0;u<4;u++){
        #pragma unroll
        for (int fj=0;fj<3;fj++){
          float bv = lw[kk+u][tf*3+fj];
          #pragma unroll
          for (int mi=0;mi<8;mi++) acc[mi][fj] = fmaf(av[mi][u], bv, acc[mi][fj]);
        }
      }
    }
    __syncthreads();
  }
  // stage conv-out tile into lw (done with weights)
  #pragma unroll
  for (int mi=0;mi<8;mi++)
    #pragma unroll
    for (int fj=0;fj<3;fj++)
      lw[tg*8+mi][tf*3+fj] = acc[mi][fj];
  __syncthreads();
  int m = t>>2, q = t&3;
  int node = m0 + m;
  if (node < dend){
    const float* xr = x1 + (size_t)node*76;
    float* xo = x2 + (size_t)node*76;
    for (int cc=q*19; cc<q*19+19; cc++){
      float v;
      if (cc < 12){
        float y = lw[m][cc];
        v = (cc<4) ? fmaxf(y,0.f) : fabsf(y);
      } else {
        int j = cc-12;
        int gi = (j<24) ? (j/3) : (8 + (j-24)/5);
        float gy = lw[m][12+gi];
        float ga = (gi<4 || (gi>=8 && gi<12)) ? fmaxf(gy,0.f) : tanhf(gy);
        v = lw[m][28+j]*ga;
      }
      xo[cc] = v + xr[cc];
    }
  }
}

// ---------------- launch ----------------

extern "C" void kernel_launch(void* const* d_in, const int* in_sizes, int n_in,
                              void* d_out, int out_size, void* d_ws, size_t ws_size,
                              hipStream_t stream){
  const int*   types = (const int*)d_in[0];
  const float* pos   = (const float*)d_in[1];
  const int*   esrc  = (const int*)d_in[2];
  const int*   edst  = (const int*)d_in[3];
  const float* embed = (const float*)d_in[4];
  const float* m1w1=(const float*)d_in[5],  *m1w2=(const float*)d_in[6],  *tp1=(const float*)d_in[7];
  const float* m2w1=(const float*)d_in[8],  *m2w2=(const float*)d_in[9],  *tp2=(const float*)d_in[10];
  const float* m3w1=(const float*)d_in[11], *m3w2=(const float*)d_in[12], *tp3=(const float*)d_in[13];
  int N = in_sizes[0];
  int E = in_sizes[2];
  float* out = (float*)d_out;

  char* wsb = (char*)d_ws; size_t off = 0;
  auto alloc = [&](size_t b)->char*{ char* p = wsb + off; off = (off + b + 255) & ~(size_t)255; return p; };
  float* x1      = (float*)alloc((size_t)N*76*sizeof(float));
  float* x2      = (float*)alloc((size_t)N*76*sizeof(float));
  float* shw     = (float*)alloc((size_t)E*9*sizeof(float));   // reused for layers 1,2
  int*   csr_src = (int*)alloc((size_t)E*sizeof(int));
  int*   csr_dst = (int*)alloc((size_t)E*sizeof(int));
  int*   offsets = (int*)alloc((size_t)(N+1)*sizeof(int));
  int*   counts  = (int*)alloc((size_t)N*sizeof(int));
  int*   cursor  = (int*)alloc((size_t)N*sizeof(int));
  int*   excl    = (int*)alloc((size_t)N*sizeof(int));
  int*   bsum    = (int*)alloc(1024*sizeof(int));
  float* Wp      = (float*)alloc((size_t)704*96*sizeof(float));
  float* G       = (float*)alloc((size_t)N*9*sizeof(float));

  // elastic Z2 chunk: whatever workspace remains, capped, multiple of 64
  size_t avail = (ws_size > off) ? (ws_size - off - 512) : 0;
  long long rows = (long long)(avail / (704*sizeof(float))) - 64;
  int CH = (rows > 12544) ? 12544 : (int)rows;
  CH = (CH / 64) * 64;
  if (CH < 64) CH = 64;   // last resort; would need ~36 MB
  float* Z2 = (float*)alloc((size_t)(CH+64)*704*sizeof(float));

  hipMemsetAsync(counts, 0, (size_t)N*sizeof(int), stream);
  hipMemsetAsync(G, 0, (size_t)N*9*sizeof(float), stream);
  hipMemsetAsync(out, 0, sizeof(float), stream);

  int nbE = (E+255)/256;
  k_count<<<nbE,256,0,stream>>>(edst, counts, E);
  int NB1 = (N+1023)/1024;
  k_scan1<<<NB1,1024,0,stream>>>(counts, excl, bsum, N);
  k_scan2<<<1,1024,0,stream>>>(bsum, NB1);
  k_scan3<<<(N+1+1023)/1024,1024,0,stream>>>(excl, bsum, offsets, cursor, N, E);
  k_geom<<<nbE,256,0,stream>>>(esrc, edst, cursor, csr_src, csr_dst, E);
  k_wprep<<<(704*96+255)/256,256,0,stream>>>(tp2, Wp);

  // layer 3 G-scatter (independent of x1/x2; natural edge order)
  k_g3<<<nbE,256,0,stream>>>(esrc, edst, pos, types, embed, m3w1, m3w2, G, E);

  // layer 1
  k_shw<<<nbE,256,0,stream>>>(csr_src, csr_dst, pos, types, embed, m1w1, m1w2, shw, E);
  k_layer1<<<(N+255)/256,256,0,stream>>>(offsets, csr_src, shw, types, embed, tp1, x1, N);

  // layer 2
  k_shw<<<nbE,256,0,stream>>>(csr_src, csr_dst, pos, types, embed, m2w1, m2w2, shw, E);
  for (int d0 = 0; d0 < N; d0 += CH){
    int dend = (d0 + CH < N) ? (d0 + CH) : N;
    int nn = dend - d0;
    k_conv2<<<(nn+3)/4,256,0,stream>>>(offsets, csr_src, shw, x1, Z2, d0, dend);
    k_gemm2<<<(nn+63)/64,256,0,stream>>>(Z2, Wp, x1, x2, d0, dend);
  }

  // layer 3 finish
  k_final<<<(N+255)/256,256,0,stream>>>(G, x2, tp3, out, N);
}

// Round 4
// 1599.916 us; speedup vs baseline: 1.3063x; 1.3063x over previous
//
#include <hip/hip_runtime.h>
#include <math.h>

// ---------------- scan / CSR build ----------------

__global__ void k_count(const int* __restrict__ key, int* __restrict__ counts, int E){
  int e = blockIdx.x*256 + threadIdx.x;
  if (e < E) atomicAdd(&counts[key[e]], 1);
}

__global__ void k_scan1(const int* __restrict__ cnt, int* __restrict__ excl,
                        int* __restrict__ bsum, int N){
  __shared__ int sm[1024];
  int tid = threadIdx.x, gid = blockIdx.x*1024 + tid;
  int v = (gid < N) ? cnt[gid] : 0;
  sm[tid] = v; __syncthreads();
  for (int off=1; off<1024; off<<=1){
    int t = (tid >= off) ? sm[tid-off] : 0;
    __syncthreads();
    sm[tid] += t;
    __syncthreads();
  }
  if (gid < N) excl[gid] = sm[tid] - v;
  if (tid == 1023) bsum[blockIdx.x] = sm[tid];
}

__global__ void k_scan2(int* __restrict__ bsum, int NB){
  __shared__ int sm[1024];
  int tid = threadIdx.x;
  int v = (tid < NB) ? bsum[tid] : 0;
  sm[tid] = v; __syncthreads();
  for (int off=1; off<1024; off<<=1){
    int t = (tid >= off) ? sm[tid-off] : 0;
    __syncthreads();
    sm[tid] += t;
    __syncthreads();
  }
  if (tid < NB) bsum[tid] = sm[tid] - v;
}

__global__ void k_scan3(const int* __restrict__ excl, const int* __restrict__ bsum,
                        int* __restrict__ offsets, int* __restrict__ cursor, int N, int E){
  int gid = blockIdx.x*1024 + threadIdx.x;
  if (gid < N){ int o = excl[gid] + bsum[gid>>10]; offsets[gid] = o; cursor[gid] = o; }
  if (gid == N) offsets[N] = E;
}

__global__ void k_geom(const int* __restrict__ esrc, const int* __restrict__ edst,
                       int* __restrict__ cursor, int* __restrict__ csr_src,
                       int* __restrict__ csr_dst, int E){
  int e = blockIdx.x*256 + threadIdx.x;
  if (e >= E) return;
  int d = edst[e];
  int p = atomicAdd(&cursor[d], 1);
  csr_src[p] = esrc[e];
  csr_dst[p] = d;
}

__global__ void k_geom2(const int* __restrict__ esrc, const int* __restrict__ edst,
                        int* __restrict__ cursor2, int* __restrict__ csr2_dst, int E){
  int e = blockIdx.x*256 + threadIdx.x;
  if (e >= E) return;
  int s = esrc[e];
  int p = atomicAdd(&cursor2[s], 1);
  csr2_dst[p] = edst[e];
}

// ---------------- shared per-edge math ----------------

__device__ __forceinline__ void edge_shw_core(
    float px, float py, float pz,
    const float* ee /*18, radial part filled here*/, float* eew,
    const float* sW1, const float* sW2, float* shw_out /*9*/){
  // (kept for clarity; real work below)
}

__device__ __forceinline__ void edge_shw(
    int s, int d, const float* __restrict__ pos,
    const int* __restrict__ types, const float* sEmb,
    const float* sW1, const float* sW2, float* shw_out /*9*/){
  float px = pos[3*d]-pos[3*s], py = pos[3*d+1]-pos[3*s+1], pz = pos[3*d+2]-pos[3*s+2];
  float r = sqrtf(px*px + py*py + pz*pz);
  float rm = fmaxf(r, 1e-9f);
  float inv = 1.f/rm;
  float ux = px*inv, uy = py*inv, uz = pz*inv;
  const float c1 = 1.7320508075688772f, c2 = 3.872983346207417f, c2b = 1.118033988749895f;
  float sh[9];
  sh[0]=1.f; sh[1]=c1*uy; sh[2]=c1*uz; sh[3]=c1*ux;
  sh[4]=c2*ux*uy; sh[5]=c2*uy*uz; sh[6]=c2b*(3.f*uz*uz-1.f); sh[7]=c2*ux*uz;
  sh[8]=0.5f*c2*(ux*ux-uy*uy);
  float ee[18];
  int ts_ = types[s], td_ = types[d];
  #pragma unroll
  for (int i=0;i<4;i++){ ee[i] = sEmb[td_*4+i]; ee[4+i] = sEmb[ts_*4+i]; }
  float xx = r * 0.2f;                    // r / CUTOFF
  float x2v = xx*xx, x3v = x2v*xx, x6 = x3v*x3v, x7 = x6*xx, x8 = x7*xx;
  float env = 1.f - 28.f*x6 + 48.f*x7 - 21.f*x8;
  const float bc = 0.6324555320336759f;   // sqrt(2/5)
  float pref = bc * env * inv;
  const float PI = 3.14159265358979323846f;
  float s1, cth;
  __sincosf(PI*xx, &s1, &cth);
  float two_c = 2.f*cth;
  float sp = 0.f, sc = s1;                // sin(0), sin(pi x)
  ee[8] = pref * sc;
  #pragma unroll
  for (int n=2;n<=10;n++){
    float sn = two_c*sc - sp;             // sin(n pi x) recurrence
    sp = sc; sc = sn;
    ee[7+n] = pref * sc;
  }
  float h[10];
  #pragma unroll
  for (int j=0;j<10;j++){
    float a = 0.f;
    #pragma unroll
    for (int k=0;k<18;k++) a = fmaf(ee[k], sW1[k*10+j], a);
    h[j] = fmaxf(a, 0.f);
  }
  #pragma unroll
  for (int sj=0;sj<9;sj++){
    float a = 0.f;
    #pragma unroll
    for (int j=0;j<10;j++) a = fmaf(h[j], sW2[j*9+sj], a);
    shw_out[sj] = sh[sj]*a;
  }
}

// ---------------- per-layer: shw in CSR order (layers 1 & 2) ----------------

__global__ __launch_bounds__(256) void k_shw(
    const int* __restrict__ csr_src, const int* __restrict__ csr_dst,
    const float* __restrict__ pos, const int* __restrict__ types,
    const float* __restrict__ embed,
    const float* __restrict__ w1, const float* __restrict__ w2,
    float* __restrict__ shw, int E){
  __shared__ float sEmb[16];
  __shared__ float sW1[180];
  __shared__ float sW2[90];
  int t = threadIdx.x;
  if (t < 16) sEmb[t] = embed[t];
  if (t < 180) sW1[t] = w1[t];
  if (t < 90)  sW2[t] = w2[t];
  __syncthreads();
  int p = blockIdx.x*256 + t;
  if (p >= E) return;
  float sw[9];
  edge_shw(csr_src[p], csr_dst[p], pos, types, sEmb, sW1, sW2, sw);
  #pragma unroll
  for (int sj=0;sj<9;sj++) shw[(size_t)p*9+sj] = sw[sj];
}

// ---------------- layer 3: G[n,s] = sum over out-edges of n of shw3 (no atomics) ----------------
// 4 lanes per source node; lane q strides edges; shfl-reduce within 4-lane group.

__global__ __launch_bounds__(256) void k_g3src(
    const int* __restrict__ off2, const int* __restrict__ csr2_dst,
    const float* __restrict__ pos, const int* __restrict__ types,
    const float* __restrict__ embed,
    const float* __restrict__ w1, const float* __restrict__ w2,
    float* __restrict__ G, int N){
  __shared__ float sEmb[16];
  __shared__ float sW1[180];
  __shared__ float sW2[90];
  int t = threadIdx.x;
  if (t < 16) sEmb[t] = embed[t];
  if (t < 180) sW1[t] = w1[t];
  if (t < 90)  sW2[t] = w2[t];
  __syncthreads();
  int gid = blockIdx.x*256 + t;
  int n = gid >> 2, q = gid & 3;
  if (n >= N) return;
  float acc[9];
  #pragma unroll
  for (int s=0;s<9;s++) acc[s]=0.f;
  float sx = pos[3*n], sy = pos[3*n+1], sz = pos[3*n+2];
  int ts_ = types[n];
  float ee[18];
  #pragma unroll
  for (int i=0;i<4;i++) ee[4+i] = sEmb[ts_*4+i];
  const float c1 = 1.7320508075688772f, c2 = 3.872983346207417f, c2b = 1.118033988749895f;
  const float bc = 0.6324555320336759f;
  const float PI = 3.14159265358979323846f;
  int b0 = off2[n], b1 = off2[n+1];
  for (int j=b0+q; j<b1; j+=4){
    int d = csr2_dst[j];
    float px = pos[3*d]-sx, py = pos[3*d+1]-sy, pz = pos[3*d+2]-sz;
    float r = sqrtf(px*px + py*py + pz*pz);
    float rm = fmaxf(r, 1e-9f);
    float inv = 1.f/rm;
    float ux = px*inv, uy = py*inv, uz = pz*inv;
    float sh[9];
    sh[0]=1.f; sh[1]=c1*uy; sh[2]=c1*uz; sh[3]=c1*ux;
    sh[4]=c2*ux*uy; sh[5]=c2*uy*uz; sh[6]=c2b*(3.f*uz*uz-1.f); sh[7]=c2*ux*uz;
    sh[8]=0.5f*c2*(ux*ux-uy*uy);
    int td_ = types[d];
    #pragma unroll
    for (int i=0;i<4;i++) ee[i] = sEmb[td_*4+i];
    float xx = r * 0.2f;
    float x2v = xx*xx, x3v = x2v*xx, x6 = x3v*x3v, x7 = x6*xx, x8 = x7*xx;
    float env = 1.f - 28.f*x6 + 48.f*x7 - 21.f*x8;
    float pref = bc * env * inv;
    float s1, cth;
    __sincosf(PI*xx, &s1, &cth);
    float two_c = 2.f*cth;
    float sp = 0.f, sc = s1;
    ee[8] = pref * sc;
    #pragma unroll
    for (int nn=2;nn<=10;nn++){
      float sn = two_c*sc - sp;
      sp = sc; sc = sn;
      ee[7+nn] = pref * sc;
    }
    float h[10];
    #pragma unroll
    for (int jj=0;jj<10;jj++){
      float a = 0.f;
      #pragma unroll
      for (int k=0;k<18;k++) a = fmaf(ee[k], sW1[k*10+jj], a);
      h[jj] = fmaxf(a, 0.f);
    }
    #pragma unroll
    for (int sj=0;sj<9;sj++){
      float a = 0.f;
      #pragma unroll
      for (int jj=0;jj<10;jj++) a = fmaf(h[jj], sW2[jj*9+sj], a);
      acc[sj] = fmaf(sh[sj], a, acc[sj]);
    }
  }
  #pragma unroll
  for (int off=2; off>0; off>>=1){
    #pragma unroll
    for (int s=0;s<9;s++) acc[s] += __shfl_down(acc[s], off, 4);
  }
  if (q == 0){
    float* gr = G + (size_t)n*9;
    #pragma unroll
    for (int s=0;s<9;s++) gr[s] = acc[s];
  }
}

// ---------------- layer 3 finish: out = 0.25 * sum_n sum_s G[n,s]*(x2[n].tp3[s]) ----------------

__global__ __launch_bounds__(256) void k_final(
    const float* __restrict__ G, const float* __restrict__ x2,
    const float* __restrict__ tp3, float* __restrict__ out, int N){
  __shared__ float tl[684];
  int t = threadIdx.x;
  for (int i=t;i<684;i+=256) tl[i] = tp3[i]*0.25f;
  __syncthreads();
  int n = blockIdx.x*256 + t;
  float part = 0.f;
  if (n < N){
    const float* xr = x2 + (size_t)n*76;
    float accs[9];
    #pragma unroll
    for (int s=0;s<9;s++) accs[s]=0.f;
    #pragma unroll
    for (int i4=0;i4<19;i4++){
      float4 xv = *(const float4*)&xr[i4*4];
      #pragma unroll
      for (int s=0;s<9;s++){
        const float* tp = &tl[s*76 + i4*4];
        accs[s] = fmaf(xv.x, tp[0], accs[s]);
        accs[s] = fmaf(xv.y, tp[1], accs[s]);
        accs[s] = fmaf(xv.z, tp[2], accs[s]);
        accs[s] = fmaf(xv.w, tp[3], accs[s]);
      }
    }
    const float* gr = G + (size_t)n*9;
    #pragma unroll
    for (int s=0;s<9;s++) part = fmaf(accs[s], gr[s], part);
  }
  #pragma unroll
  for (int off=32; off>0; off>>=1) part += __shfl_down(part, off, 64);
  if ((t & 63) == 0) atomicAdd(out, part);
}

// ---------------- layer 1: thread-per-dest (Z is 36 regs) + gate + residual ----------------

__global__ __launch_bounds__(256) void k_layer1(
    const int* __restrict__ offsets, const int* __restrict__ csr_src,
    const float* __restrict__ shw1, const int* __restrict__ types,
    const float* __restrict__ embed, const float* __restrict__ tp1,
    float* __restrict__ x1, int N){
  __shared__ float sT[36*92];
  __shared__ float sEmb[16];
  int t = threadIdx.x;
  if (t < 16) sEmb[t] = embed[t];
  for (int i=t; i<36*92; i+=256) sT[i] = tp1[i]*0.25f;   // fold 1/sqrt(AVG_DEG)
  __syncthreads();
  int d = blockIdx.x*256 + t;
  if (d >= N) return;
  float Z[36];
  #pragma unroll
  for (int i=0;i<36;i++) Z[i]=0.f;
  int b0 = offsets[d], b1 = offsets[d+1];
  for (int j=b0;j<b1;j++){
    int sn = csr_src[j];
    int tt = types[sn];
    float x0[4];
    #pragma unroll
    for (int i=0;i<4;i++) x0[i] = sEmb[tt*4+i];
    #pragma unroll
    for (int si=0;si<9;si++){
      float sw = shw1[(size_t)j*9+si];
      #pragma unroll
      for (int i=0;i<4;i++) Z[si*4+i] = fmaf(sw, x0[i], Z[si*4+i]);
    }
  }
  float sact[12];
  #pragma unroll
  for (int c=0;c<12;c++){
    float y=0.f;
    #pragma unroll
    for (int p=0;p<36;p++) y = fmaf(Z[p], sT[p*92+c], y);
    sact[c] = (c<4) ? fmaxf(y,0.f) : fabsf(y);
  }
  float gact[16];
  #pragma unroll
  for (int c=0;c<16;c++){
    float y=0.f;
    #pragma unroll
    for (int p=0;p<36;p++) y = fmaf(Z[p], sT[p*92+12+c], y);
    gact[c] = (c<4 || (c>=8 && c<12)) ? fmaxf(y,0.f) : tanhf(y);
  }
  int td = types[d];
  float* xo = x1 + (size_t)d*76;
  #pragma unroll
  for (int c=0;c<12;c++) xo[c] = sact[c] + (c<4 ? sEmb[td*4+c] : 0.f);
  #pragma unroll
  for (int j=0;j<64;j++){
    float y=0.f;
    #pragma unroll
    for (int p=0;p<36;p++) y = fmaf(Z[p], sT[p*92+28+j], y);
    int gi = (j<24) ? (j/3) : (8 + (j-24)/5);
    xo[12+j] = y*gact[gi];
  }
}

// ---------------- layer 2 stage A: wave-per-dest Z accumulation (lane = feature) ----------------

__global__ __launch_bounds__(256) void k_conv2(
    const int* __restrict__ offsets, const int* __restrict__ csr_src,
    const float* __restrict__ shw2, const float* __restrict__ x1,
    float* __restrict__ Z2, int d0, int dend){
  int lane = threadIdx.x & 63;
  int d = d0 + blockIdx.x*4 + (threadIdx.x >> 6);
  if (d >= dend) return;
  float z[9], zb[9];
  #pragma unroll
  for (int s=0;s<9;s++){ z[s]=0.f; zb[s]=0.f; }
  bool hi = lane < 12;
  int b0 = offsets[d], b1 = offsets[d+1];
  for (int j=b0;j<b1;j++){
    int sn = csr_src[j];                       // wave-uniform
    const float* xr = x1 + (size_t)sn*76;
    float xa = xr[lane];
    float xb = hi ? xr[64+lane] : 0.f;
    #pragma unroll
    for (int s=0;s<9;s++){
      float sw = shw2[(size_t)j*9+s];          // wave-uniform broadcast
      z[s]  = fmaf(sw, xa, z[s]);
      zb[s] = fmaf(sw, xb, zb[s]);
    }
  }
  float* zr = Z2 + (size_t)(d - d0)*704;
  #pragma unroll
  for (int s=0;s<9;s++){
    zr[s*76+lane] = z[s];
    if (hi) zr[s*76+64+lane] = zb[s];
  }
  if (lane < 20) zr[684+lane] = 0.f;           // K padding 684->704
}

// ---------------- layer 2 stage B: (chunk x 704) @ (704 x 96) GEMM + gate + residual ----------------

__global__ void k_wprep(const float* __restrict__ tp2, float* __restrict__ W){
  int q = blockIdx.x*256 + threadIdx.x;
  if (q >= 704*96) return;
  int k = q/96, f = q - 96*k;
  W[q] = (k < 684 && f < 92) ? tp2[k*92+f]*0.25f : 0.f;
}

__global__ __launch_bounds__(256) void k_gemm2(
    const float* __restrict__ Z2, const float* __restrict__ W,
    const float* __restrict__ x1, float* __restrict__ x2, int d0, int dend){
  __shared__ float lz[64][68];
  __shared__ float lw[64][100];
  int t = threadIdx.x;
  int mb = blockIdx.x*64;          // row within chunk
  int m0 = d0 + mb;                // global node
  int tf = t & 31, tg = t >> 5;
  float acc[8][3];
  #pragma unroll
  for (int a=0;a<8;a++)
    #pragma unroll
    for (int b=0;b<3;b++) acc[a][b]=0.f;
  for (int c=0;c<11;c++){
    #pragma unroll
    for (int j=0;j<4;j++){
      int q = j*256+t; int m = q>>4, k4 = q&15;
      *(float4*)&lz[m][k4*4] = *(const float4*)&Z2[(size_t)(mb+m)*704 + c*64 + k4*4];
    }
    #pragma unroll
    for (int j=0;j<6;j++){
      int q = j*256+t; int k = q/24, f4 = q - k*24;
      *(float4*)&lw[k][f4*4] = *(const float4*)&W[(size_t)(c*64+k)*96 + f4*4];
    }
    __syncthreads();
    #pragma unroll 2
    for (int kk=0; kk<64; kk+=4){
      float av[8][4];
      #pragma unroll
      for (int mi=0;mi<8;mi++) *(float4*)av[mi] = *(const float4*)&lz[tg*8+mi][kk];
      #pragma unroll
      for (int u=0;u<4;u++){
        #pragma unroll
        for (int fj=0;fj<3;fj++){
          float bv = lw[kk+u][tf*3+fj];
          #pragma unroll
          for (int mi=0;mi<8;mi++) acc[mi][fj] = fmaf(av[mi][u], bv, acc[mi][fj]);
        }
      }
    }
    __syncthreads();
  }
  // stage conv-out tile into lw (done with weights)
  #pragma unroll
  for (int mi=0;mi<8;mi++)
    #pragma unroll
    for (int fj=0;fj<3;fj++)
      lw[tg*8+mi][tf*3+fj] = acc[mi][fj];
  __syncthreads();
  int m = t>>2, q = t&3;
  int node = m0 + m;
  if (node < dend){
    const float* xr = x1 + (size_t)node*76;
    float* xo = x2 + (size_t)node*76;
    for (int cc=q*19; cc<q*19+19; cc++){
      float v;
      if (cc < 12){
        float y = lw[m][cc];
        v = (cc<4) ? fmaxf(y,0.f) : fabsf(y);
      } else {
        int j = cc-12;
        int gi = (j<24) ? (j/3) : (8 + (j-24)/5);
        float gy = lw[m][12+gi];
        float ga = (gi<4 || (gi>=8 && gi<12)) ? fmaxf(gy,0.f) : tanhf(gy);
        v = lw[m][28+j]*ga;
      }
      xo[cc] = v + xr[cc];
    }
  }
}

// ---------------- launch ----------------

extern "C" void kernel_launch(void* const* d_in, const int* in_sizes, int n_in,
                              void* d_out, int out_size, void* d_ws, size_t ws_size,
                              hipStream_t stream){
  const int*   types = (const int*)d_in[0];
  const float* pos   = (const float*)d_in[1];
  const int*   esrc  = (const int*)d_in[2];
  const int*   edst  = (const int*)d_in[3];
  const float* embed = (const float*)d_in[4];
  const float* m1w1=(const float*)d_in[5],  *m1w2=(const float*)d_in[6],  *tp1=(const float*)d_in[7];
  const float* m2w1=(const float*)d_in[8],  *m2w2=(const float*)d_in[9],  *tp2=(const float*)d_in[10];
  const float* m3w1=(const float*)d_in[11], *m3w2=(const float*)d_in[12], *tp3=(const float*)d_in[13];
  int N = in_sizes[0];
  int E = in_sizes[2];
  float* out = (float*)d_out;

  char* wsb = (char*)d_ws; size_t off = 0;
  auto alloc = [&](size_t b)->char*{ char* p = wsb + off; off = (off + b + 255) & ~(size_t)255; return p; };
  float* x1      = (float*)alloc((size_t)N*76*sizeof(float));
  float* x2      = (float*)alloc((size_t)N*76*sizeof(float));
  float* shw     = (float*)alloc((size_t)E*9*sizeof(float));   // reused for layers 1,2
  int*   csr_src = (int*)alloc((size_t)E*sizeof(int));
  int*   csr_dst = (int*)alloc((size_t)E*sizeof(int));
  int*   csr2_dst= (int*)alloc((size_t)E*sizeof(int));
  int*   offsets = (int*)alloc((size_t)(N+1)*sizeof(int));
  int*   off2    = (int*)alloc((size_t)(N+1)*sizeof(int));
  int*   counts  = (int*)alloc((size_t)N*sizeof(int));
  int*   counts2 = (int*)alloc((size_t)N*sizeof(int));
  int*   cursor  = (int*)alloc((size_t)N*sizeof(int));
  int*   cursor2 = (int*)alloc((size_t)N*sizeof(int));
  int*   excl    = (int*)alloc((size_t)N*sizeof(int));
  int*   bsum    = (int*)alloc(1024*sizeof(int));
  float* Wp      = (float*)alloc((size_t)704*96*sizeof(float));
  float* G       = (float*)alloc((size_t)N*9*sizeof(float));

  // elastic Z2 chunk: whatever workspace remains, capped, multiple of 64
  size_t avail = (ws_size > off) ? (ws_size - off - 512) : 0;
  long long rows = (long long)(avail / (704*sizeof(float))) - 64;
  int CH = (rows > 12544) ? 12544 : (int)rows;
  CH = (CH / 64) * 64;
  if (CH < 64) CH = 64;
  float* Z2 = (float*)alloc((size_t)(CH+64)*704*sizeof(float));

  hipMemsetAsync(counts, 0, (size_t)N*sizeof(int), stream);
  hipMemsetAsync(counts2, 0, (size_t)N*sizeof(int), stream);
  hipMemsetAsync(out, 0, sizeof(float), stream);

  int nbE = (E+255)/256;
  int NB1 = (N+1023)/1024;
  // dest-CSR
  k_count<<<nbE,256,0,stream>>>(edst, counts, E);
  k_scan1<<<NB1,1024,0,stream>>>(counts, excl, bsum, N);
  k_scan2<<<1,1024,0,stream>>>(bsum, NB1);
  k_scan3<<<(N+1+1023)/1024,1024,0,stream>>>(excl, bsum, offsets, cursor, N, E);
  k_geom<<<nbE,256,0,stream>>>(esrc, edst, cursor, csr_src, csr_dst, E);
  // src-CSR (for layer-3 G accumulation)
  k_count<<<nbE,256,0,stream>>>(esrc, counts2, E);
  k_scan1<<<NB1,1024,0,stream>>>(counts2, excl, bsum, N);
  k_scan2<<<1,1024,0,stream>>>(bsum, NB1);
  k_scan3<<<(N+1+1023)/1024,1024,0,stream>>>(excl, bsum, off2, cursor2, N, E);
  k_geom2<<<nbE,256,0,stream>>>(esrc, edst, cursor2, csr2_dst, E);

  k_wprep<<<(704*96+255)/256,256,0,stream>>>(tp2, Wp);

  // layer 3 G (atomic-free, 4 lanes per source node)
  k_g3src<<<(4*N+255)/256,256,0,stream>>>(off2, csr2_dst, pos, types, embed, m3w1, m3w2, G, N);

  // layer 1
  k_shw<<<nbE,256,0,stream>>>(csr_src, csr_dst, pos, types, embed, m1w1, m1w2, shw, E);
  k_layer1<<<(N+255)/256,256,0,stream>>>(offsets, csr_src, shw, types, embed, tp1, x1, N);

  // layer 2
  k_shw<<<nbE,256,0,stream>>>(csr_src, csr_dst, pos, types, embed, m2w1, m2w2, shw, E);
  for (int d0 = 0; d0 < N; d0 += CH){
    int dend = (d0 + CH < N) ? (d0 + CH) : N;
    int nn = dend - d0;
    k_conv2<<<(nn+3)/4,256,0,stream>>>(offsets, csr_src, shw, x1, Z2, d0, dend);
    k_gemm2<<<(nn+63)/64,256,0,stream>>>(Z2, Wp, x1, x2, d0, dend);
  }

  // layer 3 finish
  k_final<<<(N+255)/256,256,0,stream>>>(G, x2, tp3, out, N);
}

// Round 6
// 1312.422 us; speedup vs baseline: 1.5925x; 1.2191x over previous
//
#include <hip/hip_runtime.h>
#include <hip/hip_bf16.h>
#include <math.h>

typedef unsigned int uint32;

__device__ __forceinline__ uint32 pack_bf16(float a, float b){
  __hip_bfloat16 ba = __float2bfloat16(a);
  __hip_bfloat16 bb = __float2bfloat16(b);
  unsigned short ua = *reinterpret_cast<unsigned short*>(&ba);
  unsigned short ub = *reinterpret_cast<unsigned short*>(&bb);
  return (uint32)ua | ((uint32)ub << 16);
}
__device__ __forceinline__ float bf_lo(uint32 u){ return __uint_as_float(u << 16); }
__device__ __forceinline__ float bf_hi(uint32 u){ return __uint_as_float(u & 0xffff0000u); }

// ---------------- scan / CSR build ----------------

__global__ void k_count(const int* __restrict__ key, int* __restrict__ counts, int E){
  int e = blockIdx.x*256 + threadIdx.x;
  if (e < E) atomicAdd(&counts[key[e]], 1);
}

__global__ void k_scan1(const int* __restrict__ cnt, int* __restrict__ excl,
                        int* __restrict__ bsum, int N){
  __shared__ int sm[1024];
  int tid = threadIdx.x, gid = blockIdx.x*1024 + tid;
  int v = (gid < N) ? cnt[gid] : 0;
  sm[tid] = v; __syncthreads();
  for (int off=1; off<1024; off<<=1){
    int t = (tid >= off) ? sm[tid-off] : 0;
    __syncthreads();
    sm[tid] += t;
    __syncthreads();
  }
  if (gid < N) excl[gid] = sm[tid] - v;
  if (tid == 1023) bsum[blockIdx.x] = sm[tid];
}

__global__ void k_scan2(int* __restrict__ bsum, int NB){
  __shared__ int sm[1024];
  int tid = threadIdx.x;
  int v = (tid < NB) ? bsum[tid] : 0;
  sm[tid] = v; __syncthreads();
  for (int off=1; off<1024; off<<=1){
    int t = (tid >= off) ? sm[tid-off] : 0;
    __syncthreads();
    sm[tid] += t;
    __syncthreads();
  }
  if (tid < NB) bsum[tid] = sm[tid] - v;
}

__global__ void k_scan3(const int* __restrict__ excl, const int* __restrict__ bsum,
                        int* __restrict__ offsets, int* __restrict__ cursor, int N, int E){
  int gid = blockIdx.x*1024 + threadIdx.x;
  if (gid < N){ int o = excl[gid] + bsum[gid>>10]; offsets[gid] = o; cursor[gid] = o; }
  if (gid == N) offsets[N] = E;
}

__global__ void k_geom(const int* __restrict__ esrc, const int* __restrict__ edst,
                       int* __restrict__ cursor, int* __restrict__ csr_src,
                       int* __restrict__ csr_dst, int E){
  int e = blockIdx.x*256 + threadIdx.x;
  if (e >= E) return;
  int d = edst[e];
  int p = atomicAdd(&cursor[d], 1);
  csr_src[p] = esrc[e];
  csr_dst[p] = d;
}

__global__ void k_geom2(const int* __restrict__ esrc, const int* __restrict__ edst,
                        int* __restrict__ cursor2, int* __restrict__ csr2_dst, int E){
  int e = blockIdx.x*256 + threadIdx.x;
  if (e >= E) return;
  int s = esrc[e];
  int p = atomicAdd(&cursor2[s], 1);
  csr2_dst[p] = edst[e];
}

// ---------------- shared per-edge math ----------------

__device__ __forceinline__ void edge_shw(
    int s, int d, const float* __restrict__ pos,
    const int* __restrict__ types, const float* sEmb,
    const float* sW1, const float* sW2, float* shw_out /*9*/){
  float px = pos[3*d]-pos[3*s], py = pos[3*d+1]-pos[3*s+1], pz = pos[3*d+2]-pos[3*s+2];
  float r = sqrtf(px*px + py*py + pz*pz);
  float rm = fmaxf(r, 1e-9f);
  float inv = 1.f/rm;
  float ux = px*inv, uy = py*inv, uz = pz*inv;
  const float c1 = 1.7320508075688772f, c2 = 3.872983346207417f, c2b = 1.118033988749895f;
  float sh[9];
  sh[0]=1.f; sh[1]=c1*uy; sh[2]=c1*uz; sh[3]=c1*ux;
  sh[4]=c2*ux*uy; sh[5]=c2*uy*uz; sh[6]=c2b*(3.f*uz*uz-1.f); sh[7]=c2*ux*uz;
  sh[8]=0.5f*c2*(ux*ux-uy*uy);
  float ee[18];
  int ts_ = types[s], td_ = types[d];
  #pragma unroll
  for (int i=0;i<4;i++){ ee[i] = sEmb[td_*4+i]; ee[4+i] = sEmb[ts_*4+i]; }
  float xx = r * 0.2f;
  float x2v = xx*xx, x3v = x2v*xx, x6 = x3v*x3v, x7 = x6*xx, x8 = x7*xx;
  float env = 1.f - 28.f*x6 + 48.f*x7 - 21.f*x8;
  const float bc = 0.6324555320336759f;
  float pref = bc * env * inv;
  const float PI = 3.14159265358979323846f;
  float s1, cth;
  __sincosf(PI*xx, &s1, &cth);
  float two_c = 2.f*cth;
  float sp = 0.f, sc = s1;
  ee[8] = pref * sc;
  #pragma unroll
  for (int n=2;n<=10;n++){
    float sn = two_c*sc - sp;
    sp = sc; sc = sn;
    ee[7+n] = pref * sc;
  }
  float h[10];
  #pragma unroll
  for (int j=0;j<10;j++){
    float a = 0.f;
    #pragma unroll
    for (int k=0;k<18;k++) a = fmaf(ee[k], sW1[k*10+j], a);
    h[j] = fmaxf(a, 0.f);
  }
  #pragma unroll
  for (int sj=0;sj<9;sj++){
    float a = 0.f;
    #pragma unroll
    for (int j=0;j<10;j++) a = fmaf(h[j], sW2[j*9+sj], a);
    shw_out[sj] = sh[sj]*a;
  }
}

// ---------------- layer-2 shw (CSR order) ----------------

__global__ __launch_bounds__(256) void k_shw(
    const int* __restrict__ csr_src, const int* __restrict__ csr_dst,
    const float* __restrict__ pos, const int* __restrict__ types,
    const float* __restrict__ embed,
    const float* __restrict__ w1, const float* __restrict__ w2,
    float* __restrict__ shw, int E){
  __shared__ float sEmb[16];
  __shared__ float sW1[180];
  __shared__ float sW2[90];
  int t = threadIdx.x;
  if (t < 16) sEmb[t] = embed[t];
  if (t < 180) sW1[t] = w1[t];
  if (t < 90)  sW2[t] = w2[t];
  __syncthreads();
  int p = blockIdx.x*256 + t;
  if (p >= E) return;
  float sw[9];
  edge_shw(csr_src[p], csr_dst[p], pos, types, sEmb, sW1, sW2, sw);
  #pragma unroll
  for (int sj=0;sj<9;sj++) shw[(size_t)p*9+sj] = sw[sj];
}

// ---------------- layer 1 FUSED: inline shw + conv + gate + residual, 4 lanes/node ----------------

__global__ __launch_bounds__(256) void k_layer1f(
    const int* __restrict__ offsets, const int* __restrict__ csr_src,
    const float* __restrict__ pos, const int* __restrict__ types,
    const float* __restrict__ embed,
    const float* __restrict__ w1, const float* __restrict__ w2,
    const float* __restrict__ tp1, float* __restrict__ x1, int N){
  __shared__ float sT[36*92];
  __shared__ float sEmb[16];
  __shared__ float sW1[180];
  __shared__ float sW2[90];
  int t = threadIdx.x;
  if (t < 16) sEmb[t] = embed[t];
  if (t < 180) sW1[t] = w1[t];
  if (t < 90)  sW2[t] = w2[t];
  for (int i=t; i<36*92; i+=256) sT[i] = tp1[i]*0.25f;
  __syncthreads();
  int gid = blockIdx.x*256 + t;
  int n = gid >> 2, q = gid & 3;
  if (n >= N) return;
  float dx = pos[3*n], dy = pos[3*n+1], dz = pos[3*n+2];
  int td = types[n];
  const float c1 = 1.7320508075688772f, c2 = 3.872983346207417f, c2b = 1.118033988749895f;
  const float bc = 0.6324555320336759f;
  const float PI = 3.14159265358979323846f;
  float ee[18];
  #pragma unroll
  for (int i=0;i<4;i++) ee[i] = sEmb[td*4+i];      // te[edge_dest] = this node
  float Z[36];
  #pragma unroll
  for (int i=0;i<36;i++) Z[i]=0.f;
  int b0 = offsets[n], b1 = offsets[n+1];
  for (int j=b0+q; j<b1; j+=4){
    int s = csr_src[j];
    float px = dx - pos[3*s], py = dy - pos[3*s+1], pz = dz - pos[3*s+2];
    float r = sqrtf(px*px + py*py + pz*pz);
    float rm = fmaxf(r, 1e-9f);
    float inv = 1.f/rm;
    float ux = px*inv, uy = py*inv, uz = pz*inv;
    float sh[9];
    sh[0]=1.f; sh[1]=c1*uy; sh[2]=c1*uz; sh[3]=c1*ux;
    sh[4]=c2*ux*uy; sh[5]=c2*uy*uz; sh[6]=c2b*(3.f*uz*uz-1.f); sh[7]=c2*ux*uz;
    sh[8]=0.5f*c2*(ux*ux-uy*uy);
    int ts_ = types[s];
    #pragma unroll
    for (int i=0;i<4;i++) ee[4+i] = sEmb[ts_*4+i];
    float xx = r * 0.2f;
    float x2v = xx*xx, x3v = x2v*xx, x6 = x3v*x3v, x7 = x6*xx, x8 = x7*xx;
    float env = 1.f - 28.f*x6 + 48.f*x7 - 21.f*x8;
    float pref = bc * env * inv;
    float s1, cth;
    __sincosf(PI*xx, &s1, &cth);
    float two_c = 2.f*cth;
    float sp = 0.f, sc = s1;
    ee[8] = pref * sc;
    #pragma unroll
    for (int nn=2;nn<=10;nn++){
      float sn = two_c*sc - sp;
      sp = sc; sc = sn;
      ee[7+nn] = pref * sc;
    }
    float h[10];
    #pragma unroll
    for (int jj=0;jj<10;jj++){
      float a = 0.f;
      #pragma unroll
      for (int k=0;k<18;k++) a = fmaf(ee[k], sW1[k*10+jj], a);
      h[jj] = fmaxf(a, 0.f);
    }
    #pragma unroll
    for (int sj=0;sj<9;sj++){
      float a = 0.f;
      #pragma unroll
      for (int jj=0;jj<10;jj++) a = fmaf(h[jj], sW2[jj*9+sj], a);
      float shw = sh[sj]*a;
      #pragma unroll
      for (int i=0;i<4;i++) Z[sj*4+i] = fmaf(shw, ee[4+i], Z[sj*4+i]);  // x0_src = ee[4..7]
    }
  }
  // butterfly reduce over the 4-lane group (all lanes end with full Z)
  #pragma unroll
  for (int m=1; m<=2; m<<=1){
    #pragma unroll
    for (int i=0;i<36;i++) Z[i] += __shfl_xor(Z[i], m, 4);
  }
  // lane q writes x1 elements [q*19, q*19+19)
  float* xo = x1 + (size_t)n*76;
  int gi_prev = -1; float ga = 0.f;
  for (int cc=q*19; cc<q*19+19; cc++){
    float v;
    if (cc < 12){
      float y = 0.f;
      #pragma unroll
      for (int p=0;p<36;p++) y = fmaf(Z[p], sT[p*92+cc], y);
      v = (cc<4) ? (fmaxf(y,0.f) + sEmb[td*4+cc]) : fabsf(y);
    } else {
      int j = cc - 12;
      int gi = (j<24) ? (j/3) : (8 + (j-24)/5);
      if (gi != gi_prev){
        float gy = 0.f;
        #pragma unroll
        for (int p=0;p<36;p++) gy = fmaf(Z[p], sT[p*92+12+gi], gy);
        ga = (gi<4 || (gi>=8 && gi<12)) ? fmaxf(gy,0.f) : tanhf(gy);
        gi_prev = gi;
      }
      float y = 0.f;
      #pragma unroll
      for (int p=0;p<36;p++) y = fmaf(Z[p], sT[p*92+28+j], y);
      v = y*ga;
    }
    xo[cc] = v;
  }
}

// ---------------- cast x1 -> bf16 pairs (for layer-2 gathers) ----------------

__global__ void k_cast(const float* __restrict__ x1, uint32* __restrict__ x1b, int n38){
  int i = blockIdx.x*256 + threadIdx.x;
  if (i >= n38) return;
  float2 f = *(const float2*)&x1[(size_t)i*2];
  x1b[i] = pack_bf16(f.x, f.y);
}

// ---------------- layer 2 stage A: wave-per-dest, bf16 gathers, bf16 Z2 ----------------

__global__ __launch_bounds__(256) void k_conv2b(
    const int* __restrict__ offsets, const int* __restrict__ csr_src,
    const float* __restrict__ shw2, const uint32* __restrict__ x1b,
    uint32* __restrict__ Z2u, int d0, int dend){
  int lane = threadIdx.x & 63;
  int d = d0 + blockIdx.x*4 + (threadIdx.x >> 6);
  if (d >= dend) return;
  float z[9], zb[9];
  #pragma unroll
  for (int s=0;s<9;s++){ z[s]=0.f; zb[s]=0.f; }
  bool act = lane < 38;
  int b0 = offsets[d], b1 = offsets[d+1];
  for (int j=b0;j<b1;j++){
    int sn = csr_src[j];                       // wave-uniform
    uint32 u = act ? x1b[(size_t)sn*38 + lane] : 0u;
    float xa = bf_lo(u), xb = bf_hi(u);
    #pragma unroll
    for (int s=0;s<9;s++){
      float sw = shw2[(size_t)j*9+s];          // wave-uniform broadcast
      z[s]  = fmaf(sw, xa, z[s]);
      zb[s] = fmaf(sw, xb, zb[s]);
    }
  }
  uint32* zr = Z2u + (size_t)(d - d0)*352;
  if (act){
    #pragma unroll
    for (int s=0;s<9;s++) zr[s*38+lane] = pack_bf16(z[s], zb[s]);
  }
  if (lane < 10) zr[342+lane] = 0u;            // pad uints 342..351 (k 684..703)
}

// ---------------- layer 2 stage B: (chunk x 704) @ (704 x 96) GEMM + gate + residual ----------------

__global__ void k_wprep(const float* __restrict__ tp2, float* __restrict__ W){
  int q = blockIdx.x*256 + threadIdx.x;
  if (q >= 704*96) return;
  int k = q/96, f = q - 96*k;
  W[q] = (k < 684 && f < 92) ? tp2[k*92+f]*0.25f : 0.f;
}

__global__ __launch_bounds__(256) void k_gemm2b(
    const uint32* __restrict__ Z2u, const float* __restrict__ W,
    const float* __restrict__ x1, float* __restrict__ x2, int d0, int dend){
  __shared__ float lz[64][68];
  __shared__ float lw[64][100];
  int t = threadIdx.x;
  int mb = blockIdx.x*64;
  int m0 = d0 + mb;
  int tf = t & 31, tg = t >> 5;
  float acc[8][3];
  #pragma unroll
  for (int a=0;a<8;a++)
    #pragma unroll
    for (int b=0;b<3;b++) acc[a][b]=0.f;
  for (int c=0;c<11;c++){
    #pragma unroll
    for (int j=0;j<4;j++){
      int q = j*256+t; int m = q>>4, u2 = q&15;     // 64 rows x 16 uint2 = 1024 slots
      uint2 v = *(const uint2*)&Z2u[(size_t)(mb+m)*352 + c*32 + u2*2];
      float4 fv;
      fv.x = bf_lo(v.x); fv.y = bf_hi(v.x); fv.z = bf_lo(v.y); fv.w = bf_hi(v.y);
      *(float4*)&lz[m][u2*4] = fv;
    }
    #pragma unroll
    for (int j=0;j<6;j++){
      int q = j*256+t; int k = q/24, f4 = q - k*24;
      *(float4*)&lw[k][f4*4] = *(const float4*)&W[(size_t)(c*64+k)*96 + f4*4];
    }
    __syncthreads();
    #pragma unroll 2
    for (int kk=0; kk<64; kk+=4){
      float av[8][4];
      #pragma unroll
      for (int mi=0;mi<8;mi++) *(float4*)av[mi] = *(const float4*)&lz[tg*8+mi][kk];
      #pragma unroll
      for (int u=0;u<4;u++){
        #pragma unroll
        for (int fj=0;fj<3;fj++){
          float bv = lw[kk+u][tf*3+fj];
          #pragma unroll
          for (int mi=0;mi<8;mi++) acc[mi][fj] = fmaf(av[mi][u], bv, acc[mi][fj]);
        }
      }
    }
    __syncthreads();
  }
  #pragma unroll
  for (int mi=0;mi<8;mi++)
    #pragma unroll
    for (int fj=0;fj<3;fj++)
      lw[tg*8+mi][tf*3+fj] = acc[mi][fj];
  __syncthreads();
  int m = t>>2, q = t&3;
  int node = m0 + m;
  if (node < dend){
    const float* xr = x1 + (size_t)node*76;
    float* xo = x2 + (size_t)node*76;
    for (int cc=q*19; cc<q*19+19; cc++){
      float v;
      if (cc < 12){
        float y = lw[m][cc];
        v = (cc<4) ? fmaxf(y,0.f) : fabsf(y);
      } else {
        int j = cc-12;
        int gi = (j<24) ? (j/3) : (8 + (j-24)/5);
        float gy = lw[m][12+gi];
        float ga = (gi<4 || (gi>=8 && gi<12)) ? fmaxf(gy,0.f) : tanhf(gy);
        v = lw[m][28+j]*ga;
      }
      xo[cc] = v + xr[cc];
    }
  }
}

// ---------------- layer 3: G via src-CSR (atomic-free) ----------------

__global__ __launch_bounds__(256) void k_g3src(
    const int* __restrict__ off2, const int* __restrict__ csr2_dst,
    const float* __restrict__ pos, const int* __restrict__ types,
    const float* __restrict__ embed,
    const float* __restrict__ w1, const float* __restrict__ w2,
    float* __restrict__ G, int N){
  __shared__ float sEmb[16];
  __shared__ float sW1[180];
  __shared__ float sW2[90];
  int t = threadIdx.x;
  if (t < 16) sEmb[t] = embed[t];
  if (t < 180) sW1[t] = w1[t];
  if (t < 90)  sW2[t] = w2[t];
  __syncthreads();
  int gid = blockIdx.x*256 + t;
  int n = gid >> 2, q = gid & 3;
  if (n >= N) return;
  float acc[9];
  #pragma unroll
  for (int s=0;s<9;s++) acc[s]=0.f;
  float sx = pos[3*n], sy = pos[3*n+1], sz = pos[3*n+2];
  int ts_ = types[n];
  float ee[18];
  #pragma unroll
  for (int i=0;i<4;i++) ee[4+i] = sEmb[ts_*4+i];
  const float c1 = 1.7320508075688772f, c2 = 3.872983346207417f, c2b = 1.118033988749895f;
  const float bc = 0.6324555320336759f;
  const float PI = 3.14159265358979323846f;
  int b0 = off2[n], b1 = off2[n+1];
  for (int j=b0+q; j<b1; j+=4){
    int d = csr2_dst[j];
    float px = pos[3*d]-sx, py = pos[3*d+1]-sy, pz = pos[3*d+2]-sz;
    float r = sqrtf(px*px + py*py + pz*pz);
    float rm = fmaxf(r, 1e-9f);
    float inv = 1.f/rm;
    float ux = px*inv, uy = py*inv, uz = pz*inv;
    float sh[9];
    sh[0]=1.f; sh[1]=c1*uy; sh[2]=c1*uz; sh[3]=c1*ux;
    sh[4]=c2*ux*uy; sh[5]=c2*uy*uz; sh[6]=c2b*(3.f*uz*uz-1.f); sh[7]=c2*ux*uz;
    sh[8]=0.5f*c2*(ux*ux-uy*uy);
    int td_ = types[d];
    #pragma unroll
    for (int i=0;i<4;i++) ee[i] = sEmb[td_*4+i];
    float xx = r * 0.2f;
    float x2v = xx*xx, x3v = x2v*xx, x6 = x3v*x3v, x7 = x6*xx, x8 = x7*xx;
    float env = 1.f - 28.f*x6 + 48.f*x7 - 21.f*x8;
    float pref = bc * env * inv;
    float s1, cth;
    __sincosf(PI*xx, &s1, &cth);
    float two_c = 2.f*cth;
    float sp = 0.f, sc = s1;
    ee[8] = pref * sc;
    #pragma unroll
    for (int nn=2;nn<=10;nn++){
      float sn = two_c*sc - sp;
      sp = sc; sc = sn;
      ee[7+nn] = pref * sc;
    }
    float h[10];
    #pragma unroll
    for (int jj=0;jj<10;jj++){
      float a = 0.f;
      #pragma unroll
      for (int k=0;k<18;k++) a = fmaf(ee[k], sW1[k*10+jj], a);
      h[jj] = fmaxf(a, 0.f);
    }
    #pragma unroll
    for (int sj=0;sj<9;sj++){
      float a = 0.f;
      #pragma unroll
      for (int jj=0;jj<10;jj++) a = fmaf(h[jj], sW2[jj*9+sj], a);
      acc[sj] = fmaf(sh[sj], a, acc[sj]);
    }
  }
  #pragma unroll
  for (int off=2; off>0; off>>=1){
    #pragma unroll
    for (int s=0;s<9;s++) acc[s] += __shfl_down(acc[s], off, 4);
  }
  if (q == 0){
    float* gr = G + (size_t)n*9;
    #pragma unroll
    for (int s=0;s<9;s++) gr[s] = acc[s];
  }
}

// ---------------- layer 3 finish ----------------

__global__ __launch_bounds__(256) void k_final(
    const float* __restrict__ G, const float* __restrict__ x2,
    const float* __restrict__ tp3, float* __restrict__ out, int N){
  __shared__ float tl[684];
  int t = threadIdx.x;
  for (int i=t;i<684;i+=256) tl[i] = tp3[i]*0.25f;
  __syncthreads();
  int n = blockIdx.x*256 + t;
  float part = 0.f;
  if (n < N){
    const float* xr = x2 + (size_t)n*76;
    float accs[9];
    #pragma unroll
    for (int s=0;s<9;s++) accs[s]=0.f;
    #pragma unroll
    for (int i4=0;i4<19;i4++){
      float4 xv = *(const float4*)&xr[i4*4];
      #pragma unroll
      for (int s=0;s<9;s++){
        const float* tp = &tl[s*76 + i4*4];
        accs[s] = fmaf(xv.x, tp[0], accs[s]);
        accs[s] = fmaf(xv.y, tp[1], accs[s]);
        accs[s] = fmaf(xv.z, tp[2], accs[s]);
        accs[s] = fmaf(xv.w, tp[3], accs[s]);
      }
    }
    const float* gr = G + (size_t)n*9;
    #pragma unroll
    for (int s=0;s<9;s++) part = fmaf(accs[s], gr[s], part);
  }
  #pragma unroll
  for (int off=32; off>0; off>>=1) part += __shfl_down(part, off, 64);
  if ((t & 63) == 0) atomicAdd(out, part);
}

// ---------------- launch ----------------

extern "C" void kernel_launch(void* const* d_in, const int* in_sizes, int n_in,
                              void* d_out, int out_size, void* d_ws, size_t ws_size,
                              hipStream_t stream){
  const int*   types = (const int*)d_in[0];
  const float* pos   = (const float*)d_in[1];
  const int*   esrc  = (const int*)d_in[2];
  const int*   edst  = (const int*)d_in[3];
  const float* embed = (const float*)d_in[4];
  const float* m1w1=(const float*)d_in[5],  *m1w2=(const float*)d_in[6],  *tp1=(const float*)d_in[7];
  const float* m2w1=(const float*)d_in[8],  *m2w2=(const float*)d_in[9],  *tp2=(const float*)d_in[10];
  const float* m3w1=(const float*)d_in[11], *m3w2=(const float*)d_in[12], *tp3=(const float*)d_in[13];
  int N = in_sizes[0];
  int E = in_sizes[2];
  float* out = (float*)d_out;

  char* wsb = (char*)d_ws; size_t off = 0;
  auto alloc = [&](size_t b)->char*{ char* p = wsb + off; off = (off + b + 255) & ~(size_t)255; return p; };
  float*  x1      = (float*)alloc((size_t)N*76*sizeof(float));
  float*  x2      = (float*)alloc((size_t)N*76*sizeof(float));
  uint32* x1b     = (uint32*)alloc((size_t)N*38*sizeof(uint32));
  float*  shw     = (float*)alloc((size_t)E*9*sizeof(float));
  int*    csr_src = (int*)alloc((size_t)E*sizeof(int));
  int*    csr_dst = (int*)alloc((size_t)E*sizeof(int));
  int*    csr2_dst= (int*)alloc((size_t)E*sizeof(int));
  int*    offsets = (int*)alloc((size_t)(N+1)*sizeof(int));
  int*    off2    = (int*)alloc((size_t)(N+1)*sizeof(int));
  int*    counts  = (int*)alloc((size_t)N*sizeof(int));
  int*    counts2 = (int*)alloc((size_t)N*sizeof(int));
  int*    cursor  = (int*)alloc((size_t)N*sizeof(int));
  int*    cursor2 = (int*)alloc((size_t)N*sizeof(int));
  int*    excl    = (int*)alloc((size_t)N*sizeof(int));
  int*    bsum    = (int*)alloc(1024*sizeof(int));
  float*  Wp      = (float*)alloc((size_t)704*96*sizeof(float));
  float*  G       = (float*)alloc((size_t)N*9*sizeof(float));

  // elastic bf16 Z2 chunk
  size_t avail = (ws_size > off) ? (ws_size - off - 512) : 0;
  long long rows = (long long)(avail / (352*sizeof(uint32))) - 64;
  int CH = (rows > 25088) ? 25088 : (int)rows;
  CH = (CH / 64) * 64;
  if (CH < 64) CH = 64;
  uint32* Z2u = (uint32*)alloc((size_t)(CH+64)*352*sizeof(uint32));

  hipMemsetAsync(counts, 0, (size_t)N*sizeof(int), stream);
  hipMemsetAsync(counts2, 0, (size_t)N*sizeof(int), stream);
  hipMemsetAsync(out, 0, sizeof(float), stream);

  int nbE = (E+255)/256;
  int NB1 = (N+1023)/1024;
  // dest-CSR
  k_count<<<nbE,256,0,stream>>>(edst, counts, E);
  k_scan1<<<NB1,1024,0,stream>>>(counts, excl, bsum, N);
  k_scan2<<<1,1024,0,stream>>>(bsum, NB1);
  k_scan3<<<(N+1+1023)/1024,1024,0,stream>>>(excl, bsum, offsets, cursor, N, E);
  k_geom<<<nbE,256,0,stream>>>(esrc, edst, cursor, csr_src, csr_dst, E);
  // src-CSR
  k_count<<<nbE,256,0,stream>>>(esrc, counts2, E);
  k_scan1<<<NB1,1024,0,stream>>>(counts2, excl, bsum, N);
  k_scan2<<<1,1024,0,stream>>>(bsum, NB1);
  k_scan3<<<(N+1+1023)/1024,1024,0,stream>>>(excl, bsum, off2, cursor2, N, E);
  k_geom2<<<nbE,256,0,stream>>>(esrc, edst, cursor2, csr2_dst, E);

  k_wprep<<<(704*96+255)/256,256,0,stream>>>(tp2, Wp);

  // layer 3 G (atomic-free)
  k_g3src<<<(4*N+255)/256,256,0,stream>>>(off2, csr2_dst, pos, types, embed, m3w1, m3w2, G, N);

  // layer 1 (fused shw + conv + gate + residual)
  k_layer1f<<<(4*N+255)/256,256,0,stream>>>(offsets, csr_src, pos, types, embed,
                                            m1w1, m1w2, tp1, x1, N);
  k_cast<<<(N*38+255)/256,256,0,stream>>>(x1, x1b, N*38);

  // layer 2
  k_shw<<<nbE,256,0,stream>>>(csr_src, csr_dst, pos, types, embed, m2w1, m2w2, shw, E);
  for (int d0 = 0; d0 < N; d0 += CH){
    int dend = (d0 + CH < N) ? (d0 + CH) : N;
    int nn = dend - d0;
    k_conv2b<<<(nn+3)/4,256,0,stream>>>(offsets, csr_src, shw, x1b, Z2u, d0, dend);
    k_gemm2b<<<(nn+63)/64,256,0,stream>>>(Z2u, Wp, x1, x2, d0, dend);
  }

  // layer 3 finish
  k_final<<<(N+255)/256,256,0,stream>>>(G, x2, tp3, out, N);
}